// Round 1
// baseline (748.455 us; speedup 1.0000x reference)
//
#include <hip/hip_runtime.h>
#include <hip/hip_bf16.h>
#include <stdint.h>

// ---------------------------------------------------------------------------
// GCN forward: 3 layers of  out = Ahat * (X @ W) + b, relu between layers.
// Ahat = D^-1/2 (A + I) D^-1/2 built once (degree -> rsqrt -> CSR by dst).
// GEMM: fp32 vector-FMA, W in LDS, 8x8 register micro-tile, bf16 output.
// Aggregation: wave-per-node CSR gather of bf16 rows, f32 accumulate.
// ---------------------------------------------------------------------------

__device__ __forceinline__ float bflo(uint32_t u) { return __uint_as_float(u << 16); }
__device__ __forceinline__ float bfhi(uint32_t u) { return __uint_as_float(u & 0xffff0000u); }
__device__ __forceinline__ unsigned short f2bf(float f) {
    uint32_t x = __float_as_uint(f);
    return (unsigned short)((x + 0x7fffu + ((x >> 16) & 1u)) >> 16);
}

__global__ __launch_bounds__(256) void k_deg(const int* __restrict__ dst,
                                             int* __restrict__ deg, int E) {
    int e = blockIdx.x * 256 + threadIdx.x;
    if (e < E) atomicAdd(&deg[dst[e]], 1);
}

__global__ __launch_bounds__(256) void k_dinv(const int* __restrict__ deg,
                                              float* __restrict__ dinv, int N) {
    int i = blockIdx.x * 256 + threadIdx.x;
    if (i < N) dinv[i] = rsqrtf((float)(deg[i] + 1));  // +1 self-loop
}

// Single-block scan: 1024 threads, each owns a contiguous chunk of nodes.
__global__ __launch_bounds__(1024) void k_scan(const int* __restrict__ deg,
                                               int* __restrict__ row_ptr, int N) {
    __shared__ int part[1024];
    int t = threadIdx.x;
    int chunk = (N + 1023) >> 10;
    int lo = t * chunk;
    int hi = min(lo + chunk, N);
    int s = 0;
    for (int i = lo; i < hi; ++i) s += deg[i];
    part[t] = s;
    __syncthreads();
    for (int off = 1; off < 1024; off <<= 1) {
        int v = (t >= off) ? part[t - off] : 0;
        __syncthreads();
        part[t] += v;
        __syncthreads();
    }
    int run = (t == 0) ? 0 : part[t - 1];
    for (int i = lo; i < hi; ++i) { row_ptr[i] = run; run += deg[i]; }
    if (t == 1023) row_ptr[N] = run;
}

__global__ __launch_bounds__(256) void k_scatter(const int* __restrict__ src,
                                                 const int* __restrict__ dst,
                                                 const int* __restrict__ row_ptr,
                                                 int* __restrict__ cursor,
                                                 const float* __restrict__ dinv,
                                                 int* __restrict__ col_idx,
                                                 float* __restrict__ col_w, int E) {
    int e = blockIdx.x * 256 + threadIdx.x;
    if (e < E) {
        int s = src[e], d = dst[e];
        int pos = row_ptr[d] + atomicAdd(&cursor[d], 1);
        col_idx[pos] = s;
        col_w[pos]   = dinv[s] * dinv[d];
    }
}

// C[r,c] = sum_k A[r,k] * W[k,c];  A f32 [N,K], W f32 [K,M], H bf16 [N,M]
template <int K, int M>
__global__ __launch_bounds__(256) void k_gemm(const float* __restrict__ A,
                                              const float* __restrict__ Wm,
                                              unsigned short* __restrict__ H, int N) {
    __shared__ float Wl[K * M];
    int tid = threadIdx.x;
    for (int i = tid * 4; i < K * M; i += 256 * 4)
        *(float4*)&Wl[i] = *(const float4*)&Wm[i];
    __syncthreads();

    constexpr int TN = M / 16;              // 8 for M=128, 4 for M=64
    int ty = tid >> 4, tx = tid & 15;
    long r0 = (long)blockIdx.x * 128 + ty * 8;
    int c0 = tx * TN;

    float acc[8][TN];
#pragma unroll
    for (int i = 0; i < 8; ++i)
#pragma unroll
        for (int j = 0; j < TN; ++j) acc[i][j] = 0.f;

    long rb[8];
#pragma unroll
    for (int i = 0; i < 8; ++i) rb[i] = (r0 + i < N) ? (r0 + i) : (long)(N - 1);

    for (int kk = 0; kk < K; kk += 4) {
        float av[8][4];
#pragma unroll
        for (int i = 0; i < 8; ++i) {
            float4 t = *(const float4*)&A[rb[i] * K + kk];
            av[i][0] = t.x; av[i][1] = t.y; av[i][2] = t.z; av[i][3] = t.w;
        }
#pragma unroll
        for (int dk = 0; dk < 4; ++dk) {
            float wv[TN];
#pragma unroll
            for (int j = 0; j < TN; j += 4) {
                float4 t = *(const float4*)&Wl[(kk + dk) * M + c0 + j];
                wv[j] = t.x; wv[j + 1] = t.y; wv[j + 2] = t.z; wv[j + 3] = t.w;
            }
#pragma unroll
            for (int i = 0; i < 8; ++i)
#pragma unroll
                for (int j = 0; j < TN; ++j)
                    acc[i][j] = fmaf(av[i][dk], wv[j], acc[i][j]);
        }
    }

#pragma unroll
    for (int i = 0; i < 8; ++i) {
        if (r0 + i < N) {
            unsigned int w[TN / 2];
#pragma unroll
            for (int j = 0; j < TN; j += 2)
                w[j / 2] = (unsigned int)f2bf(acc[i][j]) |
                           ((unsigned int)f2bf(acc[i][j + 1]) << 16);
            unsigned short* dp = &H[(r0 + i) * M + c0];
            if constexpr (TN == 8) {
                uint4 v; v.x = w[0]; v.y = w[1]; v.z = w[2]; v.w = w[3];
                *(uint4*)dp = v;
            } else {
                uint2 v; v.x = w[0]; v.y = w[1];
                *(uint2*)dp = v;
            }
        }
    }
}

// One wave per node. F=128: lane owns 2 features (uint32 gather of bf16x2).
// F=64: lane owns 1 feature.
template <int F, bool RELU>
__global__ __launch_bounds__(256) void k_agg(const unsigned short* __restrict__ H,
                                             const int* __restrict__ row_ptr,
                                             const int* __restrict__ col_idx,
                                             const float* __restrict__ col_w,
                                             const float* __restrict__ dinv,
                                             const float* __restrict__ bias,
                                             float* __restrict__ Y, int N) {
    int lane = threadIdx.x & 63;
    int node = blockIdx.x * 4 + (threadIdx.x >> 6);
    if (node >= N) return;

    float wself = dinv[node];
    wself *= wself;

    float acc0, acc1 = 0.f;
    if constexpr (F == 128) {
        uint32_t u = *(const uint32_t*)&H[(size_t)node * 128 + lane * 2];
        acc0 = wself * bflo(u);
        acc1 = wself * bfhi(u);
    } else {
        acc0 = wself * bflo((uint32_t)H[(size_t)node * F + lane]);
    }

    int start = row_ptr[node], end = row_ptr[node + 1];
    for (int base = start; base < end; base += 64) {
        int n = end - base;
        int sidx = 0; float wgt = 0.f;
        if (lane < n) { sidx = col_idx[base + lane]; wgt = col_w[base + lane]; }
        int cnt = n < 64 ? n : 64;
        int j = 0;
        for (; j + 4 <= cnt; j += 4) {
            int   s0 = __shfl(sidx, j),     s1 = __shfl(sidx, j + 1);
            int   s2 = __shfl(sidx, j + 2), s3 = __shfl(sidx, j + 3);
            float w0 = __shfl(wgt, j),      w1 = __shfl(wgt, j + 1);
            float w2 = __shfl(wgt, j + 2),  w3 = __shfl(wgt, j + 3);
            if constexpr (F == 128) {
                uint32_t u0 = *(const uint32_t*)&H[(size_t)s0 * 128 + lane * 2];
                uint32_t u1 = *(const uint32_t*)&H[(size_t)s1 * 128 + lane * 2];
                uint32_t u2 = *(const uint32_t*)&H[(size_t)s2 * 128 + lane * 2];
                uint32_t u3 = *(const uint32_t*)&H[(size_t)s3 * 128 + lane * 2];
                acc0 = fmaf(w0, bflo(u0), acc0); acc1 = fmaf(w0, bfhi(u0), acc1);
                acc0 = fmaf(w1, bflo(u1), acc0); acc1 = fmaf(w1, bfhi(u1), acc1);
                acc0 = fmaf(w2, bflo(u2), acc0); acc1 = fmaf(w2, bfhi(u2), acc1);
                acc0 = fmaf(w3, bflo(u3), acc0); acc1 = fmaf(w3, bfhi(u3), acc1);
            } else {
                float h0 = bflo((uint32_t)H[(size_t)s0 * F + lane]);
                float h1 = bflo((uint32_t)H[(size_t)s1 * F + lane]);
                float h2 = bflo((uint32_t)H[(size_t)s2 * F + lane]);
                float h3 = bflo((uint32_t)H[(size_t)s3 * F + lane]);
                acc0 = fmaf(w0, h0, acc0); acc0 = fmaf(w1, h1, acc0);
                acc0 = fmaf(w2, h2, acc0); acc0 = fmaf(w3, h3, acc0);
            }
        }
        for (; j < cnt; ++j) {
            int   s = __shfl(sidx, j);
            float w = __shfl(wgt, j);
            if constexpr (F == 128) {
                uint32_t u = *(const uint32_t*)&H[(size_t)s * 128 + lane * 2];
                acc0 = fmaf(w, bflo(u), acc0);
                acc1 = fmaf(w, bfhi(u), acc1);
            } else {
                acc0 = fmaf(w, bflo((uint32_t)H[(size_t)s * F + lane]), acc0);
            }
        }
    }

    if constexpr (F == 128) {
        float2 b = *(const float2*)&bias[lane * 2];
        float y0 = acc0 + b.x, y1 = acc1 + b.y;
        if (RELU) { y0 = fmaxf(y0, 0.f); y1 = fmaxf(y1, 0.f); }
        float2 o; o.x = y0; o.y = y1;
        *(float2*)&Y[(size_t)node * 128 + lane * 2] = o;
    } else {
        float y = acc0 + bias[lane];
        if (RELU) y = fmaxf(y, 0.f);
        Y[(size_t)node * F + lane] = y;
    }
}

extern "C" void kernel_launch(void* const* d_in, const int* in_sizes, int n_in,
                              void* d_out, int out_size, void* d_ws, size_t ws_size,
                              hipStream_t stream) {
    const float* x  = (const float*)d_in[0];
    const int* eidx = (const int*)d_in[1];
    const float* W0 = (const float*)d_in[2];
    const float* b0 = (const float*)d_in[3];
    const float* W1 = (const float*)d_in[4];
    const float* b1 = (const float*)d_in[5];
    const float* W2 = (const float*)d_in[6];
    const float* b2 = (const float*)d_in[7];
    float* out = (float*)d_out;

    const int N = in_sizes[0] / 128;
    const int E = in_sizes[1] / 2;
    const int* srcp = eidx;
    const int* dstp = eidx + E;

    char* p = (char*)d_ws;
    auto take = [&](size_t bytes) {
        char* r = p;
        p += (bytes + 255) & ~(size_t)255;
        return r;
    };
    int*            deg     = (int*)take((size_t)N * 4);
    int*            cursor  = (int*)take((size_t)N * 4);
    int*            row_ptr = (int*)take((size_t)(N + 1) * 4);
    float*          dinv    = (float*)take((size_t)N * 4);
    int*            col_idx = (int*)take((size_t)E * 4);
    float*          col_w   = (float*)take((size_t)E * 4);
    unsigned short* hbuf    = (unsigned short*)take((size_t)N * 128 * 2);
    float*          ybuf    = (float*)take((size_t)N * 128 * 4);

    hipMemsetAsync(deg, 0, (size_t)N * 4, stream);
    hipMemsetAsync(cursor, 0, (size_t)N * 4, stream);

    k_deg<<<(E + 255) / 256, 256, 0, stream>>>(dstp, deg, E);
    k_dinv<<<(N + 255) / 256, 256, 0, stream>>>(deg, dinv, N);
    k_scan<<<1, 1024, 0, stream>>>(deg, row_ptr, N);
    k_scatter<<<(E + 255) / 256, 256, 0, stream>>>(srcp, dstp, row_ptr, cursor,
                                                   dinv, col_idx, col_w, E);

    int gemm_grid = (N + 127) / 128;
    int agg_grid  = (N + 3) / 4;

    // layer 0: h = x@W0 ; y = Ahat h + b0 ; relu
    k_gemm<128, 128><<<gemm_grid, 256, 0, stream>>>(x, W0, hbuf, N);
    k_agg<128, true><<<agg_grid, 256, 0, stream>>>(hbuf, row_ptr, col_idx, col_w,
                                                   dinv, b0, ybuf, N);
    // layer 1
    k_gemm<128, 128><<<gemm_grid, 256, 0, stream>>>(ybuf, W1, hbuf, N);
    k_agg<128, true><<<agg_grid, 256, 0, stream>>>(hbuf, row_ptr, col_idx, col_w,
                                                   dinv, b1, ybuf, N);
    // layer 2 (64-wide, no relu, straight to d_out)
    k_gemm<128, 64><<<gemm_grid, 256, 0, stream>>>(ybuf, W2, hbuf, N);
    k_agg<64, false><<<agg_grid, 256, 0, stream>>>(hbuf, row_ptr, col_idx, col_w,
                                                   dinv, b2, out, N);
}

// Round 2
// 589.420 us; speedup vs baseline: 1.2698x; 1.2698x over previous
//
#include <hip/hip_runtime.h>
#include <hip/hip_bf16.h>
#include <stdint.h>

// ---------------------------------------------------------------------------
// GCN forward: 3 layers of  out = Ahat * (X @ W) + b, relu between layers.
// Ahat = D^-1/2 (A + I) D^-1/2 built once (degree -> rsqrt -> CSR by dst).
// GEMM: fp32 vector-FMA, W in LDS, 8x8 register micro-tile, bf16 output.
// Aggregation: wave-per-node CSR gather of bf16 rows, f32 accumulate.
// Scan: 3-pass hierarchical (block scan -> tops scan -> final add).
// ---------------------------------------------------------------------------

__device__ __forceinline__ float bflo(uint32_t u) { return __uint_as_float(u << 16); }
__device__ __forceinline__ float bfhi(uint32_t u) { return __uint_as_float(u & 0xffff0000u); }
__device__ __forceinline__ unsigned short f2bf(float f) {
    uint32_t x = __float_as_uint(f);
    return (unsigned short)((x + 0x7fffu + ((x >> 16) & 1u)) >> 16);
}

__global__ __launch_bounds__(256) void k_deg(const int* __restrict__ dst,
                                             int* __restrict__ deg, int E) {
    int e = blockIdx.x * 256 + threadIdx.x;
    if (e < E) atomicAdd(&deg[dst[e]], 1);
}

__global__ __launch_bounds__(256) void k_dinv(const int* __restrict__ deg,
                                              float* __restrict__ dinv, int N) {
    int i = blockIdx.x * 256 + threadIdx.x;
    if (i < N) dinv[i] = rsqrtf((float)(deg[i] + 1));  // +1 self-loop
}

// ---- hierarchical scan: 1024 elements per block ---------------------------
__global__ __launch_bounds__(256) void k_scan_local(const int* __restrict__ deg,
                                                    int* __restrict__ incl,
                                                    int* __restrict__ bsum, int N) {
    __shared__ int part[256];
    int t = threadIdx.x;
    int idx0 = blockIdx.x * 1024 + t * 4;
    int4 lv = {0, 0, 0, 0};
    if (idx0 + 4 <= N) {
        lv = *(const int4*)&deg[idx0];
    } else {
        int* pv = (int*)&lv;
        for (int i = 0; i < 4; ++i) pv[i] = (idx0 + i < N) ? deg[idx0 + i] : 0;
    }
    int s = lv.x + lv.y + lv.z + lv.w;
    part[t] = s;
    __syncthreads();
    for (int off = 1; off < 256; off <<= 1) {
        int x = (t >= off) ? part[t - off] : 0;
        __syncthreads();
        part[t] += x;
        __syncthreads();
    }
    int run = (t == 0) ? 0 : part[t - 1];
    if (t == 255) bsum[blockIdx.x] = part[255];
    int4 ov;
    ov.x = run + lv.x;
    ov.y = ov.x + lv.y;
    ov.z = ov.y + lv.z;
    ov.w = ov.z + lv.w;
    if (idx0 + 4 <= N) {
        *(int4*)&incl[idx0] = ov;
    } else {
        int* po = (int*)&ov;
        for (int i = 0; i < 4; ++i)
            if (idx0 + i < N) incl[idx0 + i] = po[i];
    }
}

// exclusive scan of up to 256 block sums; also writes row_ptr[N] = total
__global__ __launch_bounds__(256) void k_scan_tops(int* __restrict__ bsum, int nb,
                                                   int* __restrict__ row_ptr, int N) {
    __shared__ int part[256];
    int t = threadIdx.x;
    int v = (t < nb) ? bsum[t] : 0;
    part[t] = v;
    __syncthreads();
    for (int off = 1; off < 256; off <<= 1) {
        int x = (t >= off) ? part[t - off] : 0;
        __syncthreads();
        part[t] += x;
        __syncthreads();
    }
    if (t < nb) bsum[t] = part[t] - v;   // exclusive
    if (t == 255) row_ptr[N] = part[255];
}

__global__ __launch_bounds__(256) void k_scan_final(const int* __restrict__ incl,
                                                    const int* __restrict__ deg,
                                                    const int* __restrict__ bsum,
                                                    int* __restrict__ row_ptr, int N) {
    int i = blockIdx.x * 256 + threadIdx.x;
    if (i < N) row_ptr[i] = incl[i] - deg[i] + bsum[i >> 10];
}

__global__ __launch_bounds__(256) void k_scatter(const int* __restrict__ src,
                                                 const int* __restrict__ dst,
                                                 const int* __restrict__ row_ptr,
                                                 int* __restrict__ cursor,
                                                 const float* __restrict__ dinv,
                                                 int* __restrict__ col_idx,
                                                 float* __restrict__ col_w, int E) {
    int e = blockIdx.x * 256 + threadIdx.x;
    if (e < E) {
        int s = src[e], d = dst[e];
        int pos = row_ptr[d] + atomicAdd(&cursor[d], 1);
        col_idx[pos] = s;
        col_w[pos]   = dinv[s] * dinv[d];
    }
}

// C[r,c] = sum_k A[r,k] * W[k,c];  A f32 [N,K], W f32 [K,M], H bf16 [N,M]
template <int K, int M>
__global__ __launch_bounds__(256) void k_gemm(const float* __restrict__ A,
                                              const float* __restrict__ Wm,
                                              unsigned short* __restrict__ H, int N) {
    __shared__ float Wl[K * M];
    int tid = threadIdx.x;
    for (int i = tid * 4; i < K * M; i += 256 * 4)
        *(float4*)&Wl[i] = *(const float4*)&Wm[i];
    __syncthreads();

    constexpr int TN = M / 16;              // 8 for M=128, 4 for M=64
    int ty = tid >> 4, tx = tid & 15;
    long r0 = (long)blockIdx.x * 128 + ty * 8;
    int c0 = tx * TN;

    float acc[8][TN];
#pragma unroll
    for (int i = 0; i < 8; ++i)
#pragma unroll
        for (int j = 0; j < TN; ++j) acc[i][j] = 0.f;

    long rb[8];
#pragma unroll
    for (int i = 0; i < 8; ++i) rb[i] = (r0 + i < N) ? (r0 + i) : (long)(N - 1);

    for (int kk = 0; kk < K; kk += 4) {
        float av[8][4];
#pragma unroll
        for (int i = 0; i < 8; ++i) {
            float4 t = *(const float4*)&A[rb[i] * K + kk];
            av[i][0] = t.x; av[i][1] = t.y; av[i][2] = t.z; av[i][3] = t.w;
        }
#pragma unroll
        for (int dk = 0; dk < 4; ++dk) {
            float wv[TN];
#pragma unroll
            for (int j = 0; j < TN; j += 4) {
                float4 t = *(const float4*)&Wl[(kk + dk) * M + c0 + j];
                wv[j] = t.x; wv[j + 1] = t.y; wv[j + 2] = t.z; wv[j + 3] = t.w;
            }
#pragma unroll
            for (int i = 0; i < 8; ++i)
#pragma unroll
                for (int j = 0; j < TN; ++j)
                    acc[i][j] = fmaf(av[i][dk], wv[j], acc[i][j]);
        }
    }

#pragma unroll
    for (int i = 0; i < 8; ++i) {
        if (r0 + i < N) {
            unsigned int w[TN / 2];
#pragma unroll
            for (int j = 0; j < TN; j += 2)
                w[j / 2] = (unsigned int)f2bf(acc[i][j]) |
                           ((unsigned int)f2bf(acc[i][j + 1]) << 16);
            unsigned short* dp = &H[(r0 + i) * M + c0];
            if constexpr (TN == 8) {
                uint4 v; v.x = w[0]; v.y = w[1]; v.z = w[2]; v.w = w[3];
                *(uint4*)dp = v;
            } else {
                uint2 v; v.x = w[0]; v.y = w[1];
                *(uint2*)dp = v;
            }
        }
    }
}

// One wave per node. F=128: lane owns 2 features (uint32 gather of bf16x2).
// F=64: lane owns 1 feature.
template <int F, bool RELU>
__global__ __launch_bounds__(256) void k_agg(const unsigned short* __restrict__ H,
                                             const int* __restrict__ row_ptr,
                                             const int* __restrict__ col_idx,
                                             const float* __restrict__ col_w,
                                             const float* __restrict__ dinv,
                                             const float* __restrict__ bias,
                                             float* __restrict__ Y, int N) {
    int lane = threadIdx.x & 63;
    int node = blockIdx.x * 4 + (threadIdx.x >> 6);
    if (node >= N) return;

    float wself = dinv[node];
    wself *= wself;

    float acc0, acc1 = 0.f;
    if constexpr (F == 128) {
        uint32_t u = *(const uint32_t*)&H[(size_t)node * 128 + lane * 2];
        acc0 = wself * bflo(u);
        acc1 = wself * bfhi(u);
    } else {
        acc0 = wself * bflo((uint32_t)H[(size_t)node * F + lane]);
    }

    int start = row_ptr[node], end = row_ptr[node + 1];
    for (int base = start; base < end; base += 64) {
        int n = end - base;
        int sidx = 0; float wgt = 0.f;
        if (lane < n) { sidx = col_idx[base + lane]; wgt = col_w[base + lane]; }
        int cnt = n < 64 ? n : 64;
        int j = 0;
        for (; j + 4 <= cnt; j += 4) {
            int   s0 = __shfl(sidx, j),     s1 = __shfl(sidx, j + 1);
            int   s2 = __shfl(sidx, j + 2), s3 = __shfl(sidx, j + 3);
            float w0 = __shfl(wgt, j),      w1 = __shfl(wgt, j + 1);
            float w2 = __shfl(wgt, j + 2),  w3 = __shfl(wgt, j + 3);
            if constexpr (F == 128) {
                uint32_t u0 = *(const uint32_t*)&H[(size_t)s0 * 128 + lane * 2];
                uint32_t u1 = *(const uint32_t*)&H[(size_t)s1 * 128 + lane * 2];
                uint32_t u2 = *(const uint32_t*)&H[(size_t)s2 * 128 + lane * 2];
                uint32_t u3 = *(const uint32_t*)&H[(size_t)s3 * 128 + lane * 2];
                acc0 = fmaf(w0, bflo(u0), acc0); acc1 = fmaf(w0, bfhi(u0), acc1);
                acc0 = fmaf(w1, bflo(u1), acc0); acc1 = fmaf(w1, bfhi(u1), acc1);
                acc0 = fmaf(w2, bflo(u2), acc0); acc1 = fmaf(w2, bfhi(u2), acc1);
                acc0 = fmaf(w3, bflo(u3), acc0); acc1 = fmaf(w3, bfhi(u3), acc1);
            } else {
                float h0 = bflo((uint32_t)H[(size_t)s0 * F + lane]);
                float h1 = bflo((uint32_t)H[(size_t)s1 * F + lane]);
                float h2 = bflo((uint32_t)H[(size_t)s2 * F + lane]);
                float h3 = bflo((uint32_t)H[(size_t)s3 * F + lane]);
                acc0 = fmaf(w0, h0, acc0); acc0 = fmaf(w1, h1, acc0);
                acc0 = fmaf(w2, h2, acc0); acc0 = fmaf(w3, h3, acc0);
            }
        }
        for (; j < cnt; ++j) {
            int   s = __shfl(sidx, j);
            float w = __shfl(wgt, j);
            if constexpr (F == 128) {
                uint32_t u = *(const uint32_t*)&H[(size_t)s * 128 + lane * 2];
                acc0 = fmaf(w, bflo(u), acc0);
                acc1 = fmaf(w, bfhi(u), acc1);
            } else {
                acc0 = fmaf(w, bflo((uint32_t)H[(size_t)s * F + lane]), acc0);
            }
        }
    }

    if constexpr (F == 128) {
        float2 b = *(const float2*)&bias[lane * 2];
        float y0 = acc0 + b.x, y1 = acc1 + b.y;
        if (RELU) { y0 = fmaxf(y0, 0.f); y1 = fmaxf(y1, 0.f); }
        float2 o; o.x = y0; o.y = y1;
        *(float2*)&Y[(size_t)node * 128 + lane * 2] = o;
    } else {
        float y = acc0 + bias[lane];
        if (RELU) y = fmaxf(y, 0.f);
        Y[(size_t)node * F + lane] = y;
    }
}

extern "C" void kernel_launch(void* const* d_in, const int* in_sizes, int n_in,
                              void* d_out, int out_size, void* d_ws, size_t ws_size,
                              hipStream_t stream) {
    const float* x  = (const float*)d_in[0];
    const int* eidx = (const int*)d_in[1];
    const float* W0 = (const float*)d_in[2];
    const float* b0 = (const float*)d_in[3];
    const float* W1 = (const float*)d_in[4];
    const float* b1 = (const float*)d_in[5];
    const float* W2 = (const float*)d_in[6];
    const float* b2 = (const float*)d_in[7];
    float* out = (float*)d_out;

    const int N = in_sizes[0] / 128;
    const int E = in_sizes[1] / 2;
    const int* srcp = eidx;
    const int* dstp = eidx + E;

    char* p = (char*)d_ws;
    auto take = [&](size_t bytes) {
        char* r = p;
        p += (bytes + 255) & ~(size_t)255;
        return r;
    };
    int*            deg     = (int*)take((size_t)N * 4);
    int*            cursor  = (int*)take((size_t)N * 4);
    int*            row_ptr = (int*)take((size_t)(N + 1) * 4);
    float*          dinv    = (float*)take((size_t)N * 4);
    int*            col_idx = (int*)take((size_t)E * 4);
    float*          col_w   = (float*)take((size_t)E * 4);
    unsigned short* hbuf    = (unsigned short*)take((size_t)N * 128 * 2);
    float*          ybuf    = (float*)take((size_t)N * 128 * 4);
    int*            incl    = (int*)take((size_t)N * 4);
    int*            bsum    = (int*)take((size_t)256 * 4);

    hipMemsetAsync(deg, 0, (size_t)N * 4, stream);
    hipMemsetAsync(cursor, 0, (size_t)N * 4, stream);

    k_deg<<<(E + 255) / 256, 256, 0, stream>>>(dstp, deg, E);
    k_dinv<<<(N + 255) / 256, 256, 0, stream>>>(deg, dinv, N);

    int nb = (N + 1023) / 1024;  // 98 for N=100000 (must be <= 256)
    k_scan_local<<<nb, 256, 0, stream>>>(deg, incl, bsum, N);
    k_scan_tops<<<1, 256, 0, stream>>>(bsum, nb, row_ptr, N);
    k_scan_final<<<(N + 255) / 256, 256, 0, stream>>>(incl, deg, bsum, row_ptr, N);

    k_scatter<<<(E + 255) / 256, 256, 0, stream>>>(srcp, dstp, row_ptr, cursor,
                                                   dinv, col_idx, col_w, E);

    int gemm_grid = (N + 127) / 128;
    int agg_grid  = (N + 3) / 4;

    // layer 0: h = x@W0 ; y = Ahat h + b0 ; relu
    k_gemm<128, 128><<<gemm_grid, 256, 0, stream>>>(x, W0, hbuf, N);
    k_agg<128, true><<<agg_grid, 256, 0, stream>>>(hbuf, row_ptr, col_idx, col_w,
                                                   dinv, b0, ybuf, N);
    // layer 1
    k_gemm<128, 128><<<gemm_grid, 256, 0, stream>>>(ybuf, W1, hbuf, N);
    k_agg<128, true><<<agg_grid, 256, 0, stream>>>(hbuf, row_ptr, col_idx, col_w,
                                                   dinv, b1, ybuf, N);
    // layer 2 (64-wide, no relu, straight to d_out)
    k_gemm<128, 64><<<gemm_grid, 256, 0, stream>>>(ybuf, W2, hbuf, N);
    k_agg<64, false><<<agg_grid, 256, 0, stream>>>(hbuf, row_ptr, col_idx, col_w,
                                                   dinv, b2, out, N);
}

// Round 3
// 545.308 us; speedup vs baseline: 1.3725x; 1.0809x over previous
//
#include <hip/hip_runtime.h>
#include <hip/hip_bf16.h>
#include <stdint.h>

// ---------------------------------------------------------------------------
// GCN forward: 3 layers of  out = Ahat * (X @ W) + b, relu between layers.
// Factored normalization: out[d] = dinv[d]*( sum_{s in in(d)} H'[s] + H'[d] ) + b
// where H'[i] = bf16( dinv[i] * (X@W)[i] ). So the CSR carries ONLY col_idx
// (no per-edge weight), and aggregation is an unweighted gather-sum.
// CSR build: fused degree+rank (sequential rank writes), hierarchical scan,
// atomic-free scatter (pos = row_ptr[dst] + rank).
// GEMM: fp32 vector-FMA, W in LDS, 8x8 register micro-tile, dinv-scaled bf16 out.
// Aggregation: wave-per-node CSR gather of bf16 rows, f32 accumulate.
// ---------------------------------------------------------------------------

__device__ __forceinline__ float bflo(uint32_t u) { return __uint_as_float(u << 16); }
__device__ __forceinline__ float bfhi(uint32_t u) { return __uint_as_float(u & 0xffff0000u); }
__device__ __forceinline__ unsigned short f2bf(float f) {
    uint32_t x = __float_as_uint(f);
    return (unsigned short)((x + 0x7fffu + ((x >> 16) & 1u)) >> 16);
}

// degree count + per-edge rank (rank write is sequential -> coalesced)
__global__ __launch_bounds__(256) void k_deg_rank(const int* __restrict__ dst,
                                                  int* __restrict__ deg,
                                                  int* __restrict__ rank, int E) {
    int e = blockIdx.x * 256 + threadIdx.x;
    if (e < E) rank[e] = atomicAdd(&deg[dst[e]], 1);
}

__global__ __launch_bounds__(256) void k_dinv(const int* __restrict__ deg,
                                              float* __restrict__ dinv, int N) {
    int i = blockIdx.x * 256 + threadIdx.x;
    if (i < N) dinv[i] = rsqrtf((float)(deg[i] + 1));  // +1 self-loop
}

// ---- hierarchical scan: 1024 elements per block ---------------------------
__global__ __launch_bounds__(256) void k_scan_local(const int* __restrict__ deg,
                                                    int* __restrict__ incl,
                                                    int* __restrict__ bsum, int N) {
    __shared__ int part[256];
    int t = threadIdx.x;
    int idx0 = blockIdx.x * 1024 + t * 4;
    int4 lv = {0, 0, 0, 0};
    if (idx0 + 4 <= N) {
        lv = *(const int4*)&deg[idx0];
    } else {
        int* pv = (int*)&lv;
        for (int i = 0; i < 4; ++i) pv[i] = (idx0 + i < N) ? deg[idx0 + i] : 0;
    }
    int s = lv.x + lv.y + lv.z + lv.w;
    part[t] = s;
    __syncthreads();
    for (int off = 1; off < 256; off <<= 1) {
        int x = (t >= off) ? part[t - off] : 0;
        __syncthreads();
        part[t] += x;
        __syncthreads();
    }
    int run = (t == 0) ? 0 : part[t - 1];
    if (t == 255) bsum[blockIdx.x] = part[255];
    int4 ov;
    ov.x = run + lv.x;
    ov.y = ov.x + lv.y;
    ov.z = ov.y + lv.z;
    ov.w = ov.z + lv.w;
    if (idx0 + 4 <= N) {
        *(int4*)&incl[idx0] = ov;
    } else {
        int* po = (int*)&ov;
        for (int i = 0; i < 4; ++i)
            if (idx0 + i < N) incl[idx0 + i] = po[i];
    }
}

// exclusive scan of up to 256 block sums; also writes row_ptr[N] = total
__global__ __launch_bounds__(256) void k_scan_tops(int* __restrict__ bsum, int nb,
                                                   int* __restrict__ row_ptr, int N) {
    __shared__ int part[256];
    int t = threadIdx.x;
    int v = (t < nb) ? bsum[t] : 0;
    part[t] = v;
    __syncthreads();
    for (int off = 1; off < 256; off <<= 1) {
        int x = (t >= off) ? part[t - off] : 0;
        __syncthreads();
        part[t] += x;
        __syncthreads();
    }
    if (t < nb) bsum[t] = part[t] - v;   // exclusive
    if (t == 255) row_ptr[N] = part[255];
}

__global__ __launch_bounds__(256) void k_scan_final(const int* __restrict__ incl,
                                                    const int* __restrict__ deg,
                                                    const int* __restrict__ bsum,
                                                    int* __restrict__ row_ptr, int N) {
    int i = blockIdx.x * 256 + threadIdx.x;
    if (i < N) row_ptr[i] = incl[i] - deg[i] + bsum[i >> 10];
}

// atomic-free scatter: pos = row_ptr[dst] + rank
__global__ __launch_bounds__(256) void k_scatter(const int* __restrict__ src,
                                                 const int* __restrict__ dst,
                                                 const int* __restrict__ rank,
                                                 const int* __restrict__ row_ptr,
                                                 int* __restrict__ col_idx, int E) {
    int e = blockIdx.x * 256 + threadIdx.x;
    if (e < E) {
        int d = dst[e];
        col_idx[row_ptr[d] + rank[e]] = src[e];
    }
}

// H[r,:] = bf16( dinv[r] * (A[r,:] @ W) );  A f32 [N,K], W f32 [K,M], H bf16 [N,M]
template <int K, int M>
__global__ __launch_bounds__(256) void k_gemm(const float* __restrict__ A,
                                              const float* __restrict__ Wm,
                                              const float* __restrict__ dinv,
                                              unsigned short* __restrict__ H, int N) {
    __shared__ float Wl[K * M];
    int tid = threadIdx.x;
    for (int i = tid * 4; i < K * M; i += 256 * 4)
        *(float4*)&Wl[i] = *(const float4*)&Wm[i];
    __syncthreads();

    constexpr int TN = M / 16;              // 8 for M=128, 4 for M=64
    int ty = tid >> 4, tx = tid & 15;
    long r0 = (long)blockIdx.x * 128 + ty * 8;
    int c0 = tx * TN;

    float acc[8][TN];
#pragma unroll
    for (int i = 0; i < 8; ++i)
#pragma unroll
        for (int j = 0; j < TN; ++j) acc[i][j] = 0.f;

    long rb[8];
#pragma unroll
    for (int i = 0; i < 8; ++i) rb[i] = (r0 + i < N) ? (r0 + i) : (long)(N - 1);

    for (int kk = 0; kk < K; kk += 4) {
        float av[8][4];
#pragma unroll
        for (int i = 0; i < 8; ++i) {
            float4 t = *(const float4*)&A[rb[i] * K + kk];
            av[i][0] = t.x; av[i][1] = t.y; av[i][2] = t.z; av[i][3] = t.w;
        }
#pragma unroll
        for (int dk = 0; dk < 4; ++dk) {
            float wv[TN];
#pragma unroll
            for (int j = 0; j < TN; j += 4) {
                float4 t = *(const float4*)&Wl[(kk + dk) * M + c0 + j];
                wv[j] = t.x; wv[j + 1] = t.y; wv[j + 2] = t.z; wv[j + 3] = t.w;
            }
#pragma unroll
            for (int i = 0; i < 8; ++i)
#pragma unroll
                for (int j = 0; j < TN; ++j)
                    acc[i][j] = fmaf(av[i][dk], wv[j], acc[i][j]);
        }
    }

#pragma unroll
    for (int i = 0; i < 8; ++i) {
        if (r0 + i < N) {
            float sc = dinv[rb[i]];
            unsigned int w[TN / 2];
#pragma unroll
            for (int j = 0; j < TN; j += 2)
                w[j / 2] = (unsigned int)f2bf(sc * acc[i][j]) |
                           ((unsigned int)f2bf(sc * acc[i][j + 1]) << 16);
            unsigned short* dp = &H[(r0 + i) * M + c0];
            if constexpr (TN == 8) {
                uint4 v; v.x = w[0]; v.y = w[1]; v.z = w[2]; v.w = w[3];
                *(uint4*)dp = v;
            } else {
                uint2 v; v.x = w[0]; v.y = w[1];
                *(uint2*)dp = v;
            }
        }
    }
}

// One wave per node. F=128: lane owns 2 features (uint32 gather of bf16x2).
// F=64: lane owns 1 feature. Unweighted sum of H' rows, then *dinv[node].
template <int F, bool RELU>
__global__ __launch_bounds__(256) void k_agg(const unsigned short* __restrict__ H,
                                             const int* __restrict__ row_ptr,
                                             const int* __restrict__ col_idx,
                                             const float* __restrict__ dinv,
                                             const float* __restrict__ bias,
                                             float* __restrict__ Y, int N) {
    int lane = threadIdx.x & 63;
    int node = blockIdx.x * 4 + (threadIdx.x >> 6);
    if (node >= N) return;

    float acc0, acc1 = 0.f;
    if constexpr (F == 128) {
        uint32_t u = *(const uint32_t*)&H[(size_t)node * 128 + lane * 2];
        acc0 = bflo(u);         // self term H'[node], weight 1
        acc1 = bfhi(u);
    } else {
        acc0 = bflo((uint32_t)H[(size_t)node * F + lane]);
    }

    int start = row_ptr[node], end = row_ptr[node + 1];
    for (int base = start; base < end; base += 64) {
        int n = end - base;
        int sidx = 0;
        if (lane < n) sidx = col_idx[base + lane];
        int cnt = n < 64 ? n : 64;
        int j = 0;
        for (; j + 4 <= cnt; j += 4) {
            int s0 = __shfl(sidx, j),     s1 = __shfl(sidx, j + 1);
            int s2 = __shfl(sidx, j + 2), s3 = __shfl(sidx, j + 3);
            if constexpr (F == 128) {
                uint32_t u0 = *(const uint32_t*)&H[(size_t)s0 * 128 + lane * 2];
                uint32_t u1 = *(const uint32_t*)&H[(size_t)s1 * 128 + lane * 2];
                uint32_t u2 = *(const uint32_t*)&H[(size_t)s2 * 128 + lane * 2];
                uint32_t u3 = *(const uint32_t*)&H[(size_t)s3 * 128 + lane * 2];
                acc0 += bflo(u0); acc1 += bfhi(u0);
                acc0 += bflo(u1); acc1 += bfhi(u1);
                acc0 += bflo(u2); acc1 += bfhi(u2);
                acc0 += bflo(u3); acc1 += bfhi(u3);
            } else {
                acc0 += bflo((uint32_t)H[(size_t)s0 * F + lane]);
                acc0 += bflo((uint32_t)H[(size_t)s1 * F + lane]);
                acc0 += bflo((uint32_t)H[(size_t)s2 * F + lane]);
                acc0 += bflo((uint32_t)H[(size_t)s3 * F + lane]);
            }
        }
        for (; j < cnt; ++j) {
            int s = __shfl(sidx, j);
            if constexpr (F == 128) {
                uint32_t u = *(const uint32_t*)&H[(size_t)s * 128 + lane * 2];
                acc0 += bflo(u);
                acc1 += bfhi(u);
            } else {
                acc0 += bflo((uint32_t)H[(size_t)s * F + lane]);
            }
        }
    }

    float dv = dinv[node];
    if constexpr (F == 128) {
        float2 b = *(const float2*)&bias[lane * 2];
        float y0 = dv * acc0 + b.x, y1 = dv * acc1 + b.y;
        if (RELU) { y0 = fmaxf(y0, 0.f); y1 = fmaxf(y1, 0.f); }
        float2 o; o.x = y0; o.y = y1;
        *(float2*)&Y[(size_t)node * 128 + lane * 2] = o;
    } else {
        float y = dv * acc0 + bias[lane];
        if (RELU) y = fmaxf(y, 0.f);
        Y[(size_t)node * F + lane] = y;
    }
}

extern "C" void kernel_launch(void* const* d_in, const int* in_sizes, int n_in,
                              void* d_out, int out_size, void* d_ws, size_t ws_size,
                              hipStream_t stream) {
    const float* x  = (const float*)d_in[0];
    const int* eidx = (const int*)d_in[1];
    const float* W0 = (const float*)d_in[2];
    const float* b0 = (const float*)d_in[3];
    const float* W1 = (const float*)d_in[4];
    const float* b1 = (const float*)d_in[5];
    const float* W2 = (const float*)d_in[6];
    const float* b2 = (const float*)d_in[7];
    float* out = (float*)d_out;

    const int N = in_sizes[0] / 128;
    const int E = in_sizes[1] / 2;
    const int* srcp = eidx;
    const int* dstp = eidx + E;

    char* p = (char*)d_ws;
    auto take = [&](size_t bytes) {
        char* r = p;
        p += (bytes + 255) & ~(size_t)255;
        return r;
    };
    int*            deg     = (int*)take((size_t)N * 4);
    int*            rank    = (int*)take((size_t)E * 4);
    int*            row_ptr = (int*)take((size_t)(N + 1) * 4);
    float*          dinv    = (float*)take((size_t)N * 4);
    int*            col_idx = (int*)take((size_t)E * 4);
    unsigned short* hbuf    = (unsigned short*)take((size_t)N * 128 * 2);
    float*          ybuf    = (float*)take((size_t)N * 128 * 4);
    int*            incl    = (int*)take((size_t)N * 4);
    int*            bsum    = (int*)take((size_t)256 * 4);

    hipMemsetAsync(deg, 0, (size_t)N * 4, stream);

    k_deg_rank<<<(E + 255) / 256, 256, 0, stream>>>(dstp, deg, rank, E);
    k_dinv<<<(N + 255) / 256, 256, 0, stream>>>(deg, dinv, N);

    int nb = (N + 1023) / 1024;  // 98 for N=100000 (must be <= 256)
    k_scan_local<<<nb, 256, 0, stream>>>(deg, incl, bsum, N);
    k_scan_tops<<<1, 256, 0, stream>>>(bsum, nb, row_ptr, N);
    k_scan_final<<<(N + 255) / 256, 256, 0, stream>>>(incl, deg, bsum, row_ptr, N);

    k_scatter<<<(E + 255) / 256, 256, 0, stream>>>(srcp, dstp, rank, row_ptr,
                                                   col_idx, E);

    int gemm_grid = (N + 127) / 128;
    int agg_grid  = (N + 3) / 4;

    // layer 0: h' = dinv*(x@W0) ; y = dinv*(sum h') + b0 ; relu
    k_gemm<128, 128><<<gemm_grid, 256, 0, stream>>>(x, W0, dinv, hbuf, N);
    k_agg<128, true><<<agg_grid, 256, 0, stream>>>(hbuf, row_ptr, col_idx,
                                                   dinv, b0, ybuf, N);
    // layer 1
    k_gemm<128, 128><<<gemm_grid, 256, 0, stream>>>(ybuf, W1, dinv, hbuf, N);
    k_agg<128, true><<<agg_grid, 256, 0, stream>>>(hbuf, row_ptr, col_idx,
                                                   dinv, b1, ybuf, N);
    // layer 2 (64-wide, no relu, straight to d_out)
    k_gemm<128, 64><<<gemm_grid, 256, 0, stream>>>(ybuf, W2, dinv, hbuf, N);
    k_agg<64, false><<<agg_grid, 256, 0, stream>>>(hbuf, row_ptr, col_idx,
                                                   dinv, b2, out, N);
}

// Round 4
// 457.298 us; speedup vs baseline: 1.6367x; 1.1925x over previous
//
#include <hip/hip_runtime.h>
#include <hip/hip_bf16.h>
#include <stdint.h>

// ---------------------------------------------------------------------------
// GCN forward: 3 layers of  out = Ahat * (X @ W) + b, relu between layers.
// Factored normalization: out[d] = dinv[d]*( sum_{s in in(d)} H'[s] + H'[d] ) + b
// where H'[i] = bf16( dinv[i] * (X@W)[i] ).
// GEMM: MFMA bf16 hi/lo split (3 mfma per product -> ~fp32 precision),
//       128-row x 64-K LDS tiles, XOR-swizzled, K-tiled x2, 64KB LDS.
// CSR build: fused degree+rank, hierarchical scan, atomic-free scatter.
// Aggregation: wave-per-node CSR gather of bf16 rows, f32 accumulate.
// ---------------------------------------------------------------------------

typedef __attribute__((ext_vector_type(8))) short bf16x8;
typedef __attribute__((ext_vector_type(4))) float f32x4;

__device__ __forceinline__ float bflo(uint32_t u) { return __uint_as_float(u << 16); }
__device__ __forceinline__ float bfhi(uint32_t u) { return __uint_as_float(u & 0xffff0000u); }
__device__ __forceinline__ unsigned short f2bf(float f) {
    uint32_t x = __float_as_uint(f);
    return (unsigned short)((x + 0x7fffu + ((x >> 16) & 1u)) >> 16);
}

// degree count + per-edge rank (rank write is sequential -> coalesced)
__global__ __launch_bounds__(256) void k_deg_rank(const int* __restrict__ dst,
                                                  int* __restrict__ deg,
                                                  int* __restrict__ rank, int E) {
    int e = blockIdx.x * 256 + threadIdx.x;
    if (e < E) rank[e] = atomicAdd(&deg[dst[e]], 1);
}

__global__ __launch_bounds__(256) void k_dinv(const int* __restrict__ deg,
                                              float* __restrict__ dinv, int N) {
    int i = blockIdx.x * 256 + threadIdx.x;
    if (i < N) dinv[i] = rsqrtf((float)(deg[i] + 1));  // +1 self-loop
}

// ---- hierarchical scan: 1024 elements per block ---------------------------
__global__ __launch_bounds__(256) void k_scan_local(const int* __restrict__ deg,
                                                    int* __restrict__ incl,
                                                    int* __restrict__ bsum, int N) {
    __shared__ int part[256];
    int t = threadIdx.x;
    int idx0 = blockIdx.x * 1024 + t * 4;
    int4 lv = {0, 0, 0, 0};
    if (idx0 + 4 <= N) {
        lv = *(const int4*)&deg[idx0];
    } else {
        int* pv = (int*)&lv;
        for (int i = 0; i < 4; ++i) pv[i] = (idx0 + i < N) ? deg[idx0 + i] : 0;
    }
    int s = lv.x + lv.y + lv.z + lv.w;
    part[t] = s;
    __syncthreads();
    for (int off = 1; off < 256; off <<= 1) {
        int x = (t >= off) ? part[t - off] : 0;
        __syncthreads();
        part[t] += x;
        __syncthreads();
    }
    int run = (t == 0) ? 0 : part[t - 1];
    if (t == 255) bsum[blockIdx.x] = part[255];
    int4 ov;
    ov.x = run + lv.x;
    ov.y = ov.x + lv.y;
    ov.z = ov.y + lv.z;
    ov.w = ov.z + lv.w;
    if (idx0 + 4 <= N) {
        *(int4*)&incl[idx0] = ov;
    } else {
        int* po = (int*)&ov;
        for (int i = 0; i < 4; ++i)
            if (idx0 + i < N) incl[idx0 + i] = po[i];
    }
}

// exclusive scan of up to 256 block sums; also writes row_ptr[N] = total
__global__ __launch_bounds__(256) void k_scan_tops(int* __restrict__ bsum, int nb,
                                                   int* __restrict__ row_ptr, int N) {
    __shared__ int part[256];
    int t = threadIdx.x;
    int v = (t < nb) ? bsum[t] : 0;
    part[t] = v;
    __syncthreads();
    for (int off = 1; off < 256; off <<= 1) {
        int x = (t >= off) ? part[t - off] : 0;
        __syncthreads();
        part[t] += x;
        __syncthreads();
    }
    if (t < nb) bsum[t] = part[t] - v;   // exclusive
    if (t == 255) row_ptr[N] = part[255];
}

__global__ __launch_bounds__(256) void k_scan_final(const int* __restrict__ incl,
                                                    const int* __restrict__ deg,
                                                    const int* __restrict__ bsum,
                                                    int* __restrict__ row_ptr, int N) {
    int i = blockIdx.x * 256 + threadIdx.x;
    if (i < N) row_ptr[i] = incl[i] - deg[i] + bsum[i >> 10];
}

// atomic-free scatter: pos = row_ptr[dst] + rank
__global__ __launch_bounds__(256) void k_scatter(const int* __restrict__ src,
                                                 const int* __restrict__ dst,
                                                 const int* __restrict__ rank,
                                                 const int* __restrict__ row_ptr,
                                                 int* __restrict__ col_idx, int E) {
    int e = blockIdx.x * 256 + threadIdx.x;
    if (e < E) {
        int d = dst[e];
        col_idx[row_ptr[d] + rank[e]] = src[e];
    }
}

// W [K][M] f32 -> Wt_hi[c][k], Wt_lo[c][k] bf16 (transposed, hi plane then lo)
__global__ __launch_bounds__(256) void k_prepw(const float* __restrict__ W0,
                                               const float* __restrict__ W1,
                                               const float* __restrict__ W2,
                                               unsigned short* __restrict__ wt0,
                                               unsigned short* __restrict__ wt1,
                                               unsigned short* __restrict__ wt2) {
    int id = blockIdx.x * 256 + threadIdx.x;
    const float* Wsrc;
    unsigned short* dst;
    int t, M, plane;
    if (id < 16384)      { t = id;         Wsrc = W0; dst = wt0; M = 128; plane = 16384; }
    else if (id < 32768) { t = id - 16384; Wsrc = W1; dst = wt1; M = 128; plane = 16384; }
    else if (id < 40960) { t = id - 32768; Wsrc = W2; dst = wt2; M = 64;  plane = 8192;  }
    else return;
    int k = (M == 128) ? (t >> 7) : (t >> 6);
    int c = (M == 128) ? (t & 127) : (t & 63);
    float v = Wsrc[k * M + c];
    unsigned short hi = f2bf(v);
    float lov = v - bflo((uint32_t)hi);
    dst[c * 128 + k]         = hi;
    dst[plane + c * 128 + k] = f2bf(lov);
}

// H[r,:] = bf16( dinv[r] * (A[r,:] @ W) ) via split-bf16 MFMA.
// A f32 [N,128]; Wt = transposed hi/lo bf16 [NCOL][128] x2; H bf16 [N,NCOL].
// Block: 256 thr / 4 waves, tile 128 rows x NCOL cols, K-tiled by 64.
template <int NCOL>
__global__ __launch_bounds__(256) void k_gemm_mfma(
    const float* __restrict__ A, const unsigned short* __restrict__ Wt,
    const float* __restrict__ dinv, unsigned short* __restrict__ H, int N) {
    constexpr int K = 128, KT = 64;
    constexpr int A_PLANE = 128 * KT;     // shorts
    constexpr int W_PLANE = NCOL * KT;
    __shared__ __align__(16) unsigned short sm[2 * A_PLANE + 2 * W_PLANE];  // 64/48 KB
    unsigned short* Ah  = sm;
    unsigned short* Al  = sm + A_PLANE;
    unsigned short* Whp = sm + 2 * A_PLANE;
    unsigned short* Wlp = sm + 2 * A_PLANE + W_PLANE;

    const int tid = threadIdx.x;
    const long r0 = (long)blockIdx.x * 128;
    const int w = tid >> 6, l = tid & 63;
    const int lr = l & 15, lk = l >> 4;
    constexpr int WR = (NCOL == 128) ? 4 : 2;          // 16-row frags per wave
    const int wrow = (NCOL == 128) ? (w >> 1) * 64 : w * 32;
    const int wcol = (NCOL == 128) ? (w & 1) * 64 : 0;

    f32x4 acc[WR][4];
#pragma unroll
    for (int i = 0; i < WR; ++i)
#pragma unroll
        for (int j = 0; j < 4; ++j) acc[i][j] = (f32x4){0.f, 0.f, 0.f, 0.f};

    for (int kt = 0; kt < 2; ++kt) {
        if (kt) __syncthreads();           // previous compute done
        // ---- stage A tile: 128 rows x 64 k, f32 -> hi/lo bf16, swizzled ----
#pragma unroll
        for (int it = 0; it < 4; ++it) {
            int id = it * 256 + tid;
            int r = id >> 3, kc = id & 7;   // 8 chunks of 8 f32 per row
            long gr = r0 + r;
            if (gr >= N) gr = N - 1;
            const float* ap = &A[gr * K + kt * KT + kc * 8];
            float4 v0 = *(const float4*)ap;
            float4 v1 = *(const float4*)(ap + 4);
            float vv[8] = {v0.x, v0.y, v0.z, v0.w, v1.x, v1.y, v1.z, v1.w};
            union { unsigned short u[8]; bf16x8 v; } ph, pl;
#pragma unroll
            for (int j = 0; j < 8; ++j) {
                unsigned short h = f2bf(vv[j]);
                ph.u[j] = h;
                pl.u[j] = f2bf(vv[j] - bflo((uint32_t)h));
            }
            int boff = r * 128 + ((kc * 16) ^ ((r & 7) << 4));
            *(bf16x8*)((char*)Ah + boff) = ph.v;
            *(bf16x8*)((char*)Al + boff) = pl.v;
        }
        // ---- stage W tile: NCOL rows x 64 k, hi+lo, swizzled ----
#pragma unroll
        for (int it = 0; it < NCOL / 32; ++it) {
            int id = it * 256 + tid;
            int c = id >> 3, kc = id & 7;
            const unsigned short* wp = &Wt[c * K + kt * KT + kc * 8];
            bf16x8 vh = *(const bf16x8*)wp;
            bf16x8 vl = *(const bf16x8*)(wp + NCOL * K);
            int boff = c * 128 + ((kc * 16) ^ ((c & 7) << 4));
            *(bf16x8*)((char*)Whp + boff) = vh;
            *(bf16x8*)((char*)Wlp + boff) = vl;
        }
        __syncthreads();
        // ---- compute: 2 k-steps of 32 ----
#pragma unroll
        for (int ks = 0; ks < 2; ++ks) {
            int kb = ks * 64 + lk * 16;
            bf16x8 bh[4], bl[4];
#pragma unroll
            for (int cf = 0; cf < 4; ++cf) {
                int c = wcol + cf * 16 + lr;
                int off = c * 128 + (kb ^ ((c & 7) << 4));
                bh[cf] = *(bf16x8*)((char*)Whp + off);
                bl[cf] = *(bf16x8*)((char*)Wlp + off);
            }
#pragma unroll
            for (int rf = 0; rf < WR; ++rf) {
                int r = wrow + rf * 16 + lr;
                int off = r * 128 + (kb ^ ((r & 7) << 4));
                bf16x8 ah = *(bf16x8*)((char*)Ah + off);
                bf16x8 al = *(bf16x8*)((char*)Al + off);
#pragma unroll
                for (int cf = 0; cf < 4; ++cf) {
                    acc[rf][cf] = __builtin_amdgcn_mfma_f32_16x16x32_bf16(ah, bh[cf], acc[rf][cf], 0, 0, 0);
                    acc[rf][cf] = __builtin_amdgcn_mfma_f32_16x16x32_bf16(al, bh[cf], acc[rf][cf], 0, 0, 0);
                    acc[rf][cf] = __builtin_amdgcn_mfma_f32_16x16x32_bf16(ah, bl[cf], acc[rf][cf], 0, 0, 0);
                }
            }
        }
    }
    // ---- epilogue: C frag (col=lane&15, row=(lane>>4)*4+reg), scale, bf16 ----
#pragma unroll
    for (int rf = 0; rf < WR; ++rf) {
        long rb = r0 + wrow + rf * 16 + lk * 4;
#pragma unroll
        for (int reg = 0; reg < 4; ++reg) {
            long r = rb + reg;
            if (r < N) {
                float dv = dinv[r];
#pragma unroll
                for (int cf = 0; cf < 4; ++cf) {
                    int c = wcol + cf * 16 + lr;
                    H[r * NCOL + c] = f2bf(dv * acc[rf][cf][reg]);
                }
            }
        }
    }
}

// One wave per node. F=128: lane owns 2 features (uint32 gather of bf16x2).
// F=64: lane owns 1 feature. Unweighted sum of H' rows, then *dinv[node].
template <int F, bool RELU>
__global__ __launch_bounds__(256) void k_agg(const unsigned short* __restrict__ H,
                                             const int* __restrict__ row_ptr,
                                             const int* __restrict__ col_idx,
                                             const float* __restrict__ dinv,
                                             const float* __restrict__ bias,
                                             float* __restrict__ Y, int N) {
    int lane = threadIdx.x & 63;
    int node = blockIdx.x * 4 + (threadIdx.x >> 6);
    if (node >= N) return;

    float acc0, acc1 = 0.f;
    if constexpr (F == 128) {
        uint32_t u = *(const uint32_t*)&H[(size_t)node * 128 + lane * 2];
        acc0 = bflo(u);         // self term H'[node], weight 1
        acc1 = bfhi(u);
    } else {
        acc0 = bflo((uint32_t)H[(size_t)node * F + lane]);
    }

    int start = row_ptr[node], end = row_ptr[node + 1];
    for (int base = start; base < end; base += 64) {
        int n = end - base;
        int sidx = 0;
        if (lane < n) sidx = col_idx[base + lane];
        int cnt = n < 64 ? n : 64;
        int j = 0;
        for (; j + 4 <= cnt; j += 4) {
            int s0 = __shfl(sidx, j),     s1 = __shfl(sidx, j + 1);
            int s2 = __shfl(sidx, j + 2), s3 = __shfl(sidx, j + 3);
            if constexpr (F == 128) {
                uint32_t u0 = *(const uint32_t*)&H[(size_t)s0 * 128 + lane * 2];
                uint32_t u1 = *(const uint32_t*)&H[(size_t)s1 * 128 + lane * 2];
                uint32_t u2 = *(const uint32_t*)&H[(size_t)s2 * 128 + lane * 2];
                uint32_t u3 = *(const uint32_t*)&H[(size_t)s3 * 128 + lane * 2];
                acc0 += bflo(u0); acc1 += bfhi(u0);
                acc0 += bflo(u1); acc1 += bfhi(u1);
                acc0 += bflo(u2); acc1 += bfhi(u2);
                acc0 += bflo(u3); acc1 += bfhi(u3);
            } else {
                acc0 += bflo((uint32_t)H[(size_t)s0 * F + lane]);
                acc0 += bflo((uint32_t)H[(size_t)s1 * F + lane]);
                acc0 += bflo((uint32_t)H[(size_t)s2 * F + lane]);
                acc0 += bflo((uint32_t)H[(size_t)s3 * F + lane]);
            }
        }
        for (; j < cnt; ++j) {
            int s = __shfl(sidx, j);
            if constexpr (F == 128) {
                uint32_t u = *(const uint32_t*)&H[(size_t)s * 128 + lane * 2];
                acc0 += bflo(u);
                acc1 += bfhi(u);
            } else {
                acc0 += bflo((uint32_t)H[(size_t)s * F + lane]);
            }
        }
    }

    float dv = dinv[node];
    if constexpr (F == 128) {
        float2 b = *(const float2*)&bias[lane * 2];
        float y0 = dv * acc0 + b.x, y1 = dv * acc1 + b.y;
        if (RELU) { y0 = fmaxf(y0, 0.f); y1 = fmaxf(y1, 0.f); }
        float2 o; o.x = y0; o.y = y1;
        *(float2*)&Y[(size_t)node * 128 + lane * 2] = o;
    } else {
        float y = dv * acc0 + bias[lane];
        if (RELU) y = fmaxf(y, 0.f);
        Y[(size_t)node * F + lane] = y;
    }
}

extern "C" void kernel_launch(void* const* d_in, const int* in_sizes, int n_in,
                              void* d_out, int out_size, void* d_ws, size_t ws_size,
                              hipStream_t stream) {
    const float* x  = (const float*)d_in[0];
    const int* eidx = (const int*)d_in[1];
    const float* W0 = (const float*)d_in[2];
    const float* b0 = (const float*)d_in[3];
    const float* W1 = (const float*)d_in[4];
    const float* b1 = (const float*)d_in[5];
    const float* W2 = (const float*)d_in[6];
    const float* b2 = (const float*)d_in[7];
    float* out = (float*)d_out;

    const int N = in_sizes[0] / 128;
    const int E = in_sizes[1] / 2;
    const int* srcp = eidx;
    const int* dstp = eidx + E;

    char* p = (char*)d_ws;
    auto take = [&](size_t bytes) {
        char* r = p;
        p += (bytes + 255) & ~(size_t)255;
        return r;
    };
    int*            deg     = (int*)take((size_t)N * 4);
    int*            rank    = (int*)take((size_t)E * 4);
    int*            row_ptr = (int*)take((size_t)(N + 1) * 4);
    float*          dinv    = (float*)take((size_t)N * 4);
    int*            col_idx = (int*)take((size_t)E * 4);
    unsigned short* hbuf    = (unsigned short*)take((size_t)N * 128 * 2);
    float*          ybuf    = (float*)take((size_t)N * 128 * 4);
    int*            incl    = (int*)take((size_t)N * 4);
    int*            bsum    = (int*)take((size_t)256 * 4);
    unsigned short* wt0     = (unsigned short*)take((size_t)2 * 16384 * 2);
    unsigned short* wt1     = (unsigned short*)take((size_t)2 * 16384 * 2);
    unsigned short* wt2     = (unsigned short*)take((size_t)2 * 8192 * 2);

    hipMemsetAsync(deg, 0, (size_t)N * 4, stream);

    k_deg_rank<<<(E + 255) / 256, 256, 0, stream>>>(dstp, deg, rank, E);
    k_dinv<<<(N + 255) / 256, 256, 0, stream>>>(deg, dinv, N);
    k_prepw<<<160, 256, 0, stream>>>(W0, W1, W2, wt0, wt1, wt2);

    int nb = (N + 1023) / 1024;  // 98 for N=100000 (must be <= 256)
    k_scan_local<<<nb, 256, 0, stream>>>(deg, incl, bsum, N);
    k_scan_tops<<<1, 256, 0, stream>>>(bsum, nb, row_ptr, N);
    k_scan_final<<<(N + 255) / 256, 256, 0, stream>>>(incl, deg, bsum, row_ptr, N);

    k_scatter<<<(E + 255) / 256, 256, 0, stream>>>(srcp, dstp, rank, row_ptr,
                                                   col_idx, E);

    int gemm_grid = (N + 127) / 128;
    int agg_grid  = (N + 3) / 4;

    // layer 0: h' = dinv*(x@W0) ; y = dinv*(sum h') + b0 ; relu
    k_gemm_mfma<128><<<gemm_grid, 256, 0, stream>>>(x, wt0, dinv, hbuf, N);
    k_agg<128, true><<<agg_grid, 256, 0, stream>>>(hbuf, row_ptr, col_idx,
                                                   dinv, b0, ybuf, N);
    // layer 1
    k_gemm_mfma<128><<<gemm_grid, 256, 0, stream>>>(ybuf, wt1, dinv, hbuf, N);
    k_agg<128, true><<<agg_grid, 256, 0, stream>>>(hbuf, row_ptr, col_idx,
                                                   dinv, b1, ybuf, N);
    // layer 2 (64-wide, no relu, straight to d_out)
    k_gemm_mfma<64><<<gemm_grid, 256, 0, stream>>>(ybuf, wt2, dinv, hbuf, N);
    k_agg<64, false><<<agg_grid, 256, 0, stream>>>(hbuf, row_ptr, col_idx,
                                                   dinv, b2, out, N);
}